// Round 7
// baseline (587.542 us; speedup 1.0000x reference)
//
#include <hip/hip_runtime.h>

#define FIN 512
#define FHID 16
#define FOUT 40
#define KC 16

// ---------------- degree ----------------

__global__ void k_count(const int* __restrict__ dst, int* __restrict__ cnt, int E) {
    int e = blockIdx.x * blockDim.x + threadIdx.x;
    if (e < E) atomicAdd(&cnt[dst[e]], 1);
}

__global__ void k_rsqrt(const int* __restrict__ cnt, float* __restrict__ dinv, int n) {
    int i = blockIdx.x * blockDim.x + threadIdx.x;
    if (i < n) dinv[i] = rsqrtf((float)(cnt[i] + 1));  // +1 self-loop
}

// ---------------- layer 1 GEMM: g = agg = (x @ W1) * dinv ----------------
// x staged via LDS with lane-consecutive coalesced loads; W1 in LDS.

__global__ __launch_bounds__(256) void k_gemm1(const float* __restrict__ x,
                                               const float* __restrict__ W1,
                                               const float* __restrict__ dinv,
                                               float* __restrict__ g,
                                               float* __restrict__ agg, int n) {
    __shared__ float Wl[FIN * FHID];     // 32 KiB
    __shared__ float xt[256][KC + 1];    // 17.4 KiB, stride 17 -> 2 lanes/bank (free)
    {
        const float4* Wv = reinterpret_cast<const float4*>(W1);
        float4* Lv = reinterpret_cast<float4*>(Wl);
        for (int i = threadIdx.x; i < FIN * FHID / 4; i += 256) Lv[i] = Wv[i];
    }

    int t = threadIdx.x;
    int rowbase = blockIdx.x * 256;
    int myrow = rowbase + t;

    float acc[FHID];
#pragma unroll
    for (int o = 0; o < FHID; ++o) acc[o] = 0.0f;

#pragma unroll 1
    for (int kc = 0; kc < FIN / KC; ++kc) {
        __syncthreads();  // also covers Wl on first iter
        // stage 256 rows x KC floats = 1024 float4; 4 per thread, lane-consecutive
#pragma unroll
        for (int j = 0; j < 4; ++j) {
            int f = t + j * 256;
            int r = f >> 2;        // KC/4 = 4 float4 per row
            int c4 = f & 3;
            int grow = rowbase + r;
            float4 xv = make_float4(0.f, 0.f, 0.f, 0.f);
            if (grow < n)
                xv = *reinterpret_cast<const float4*>(&x[(size_t)grow * FIN + kc * KC + c4 * 4]);
            xt[r][c4 * 4 + 0] = xv.x;
            xt[r][c4 * 4 + 1] = xv.y;
            xt[r][c4 * 4 + 2] = xv.z;
            xt[r][c4 * 4 + 3] = xv.w;
        }
        __syncthreads();
#pragma unroll
        for (int k = 0; k < KC; ++k) {
            float xs = xt[t][k];
            const float* wrow = &Wl[(kc * KC + k) * FHID];
#pragma unroll
            for (int o = 0; o < FHID; ++o) acc[o] = fmaf(xs, wrow[o], acc[o]);
        }
    }

    if (myrow < n) {
        float dv = dinv[myrow];
        float4* gp = reinterpret_cast<float4*>(g + (size_t)myrow * FHID);
        float4* ap = reinterpret_cast<float4*>(agg + (size_t)myrow * FHID);
#pragma unroll
        for (int q = 0; q < FHID / 4; ++q) {
            float4 v;
            v.x = acc[4 * q + 0] * dv;
            v.y = acc[4 * q + 1] * dv;
            v.z = acc[4 * q + 2] * dv;
            v.w = acc[4 * q + 3] * dv;
            gp[q] = v;
            ap[q] = v;  // self-loop init
        }
    }
}

// ---------------- edge scatter: agg[dst] += g[src], 16 threads/edge ----------------
// ZSKIP: skip exact-zero messages (post-ReLU layer-2 table is ~50% zeros).

template <bool ZSKIP>
__global__ __launch_bounds__(256) void k_scat(const int* __restrict__ src,
                                              const int* __restrict__ dst,
                                              const float* __restrict__ g,
                                              float* __restrict__ agg, int E) {
    long long tid = (long long)blockIdx.x * 256 + threadIdx.x;
    int e = (int)(tid >> 4);
    int c = (int)(tid & 15);
    if (e >= E) return;
    int s = src[e];
    int d = dst[e];
    float v = g[(size_t)s * FHID + c];
    if (!ZSKIP || v != 0.0f) atomicAdd(&agg[(size_t)d * FHID + c], v);
}

// ---------------- finish layer 1: p = aggp = relu(agg*dinv + b1) * dinv -------------

__global__ void k_finish1(const float* __restrict__ agg, const float* __restrict__ dinv,
                          const float* __restrict__ b1, float* __restrict__ p,
                          float* __restrict__ aggp, int n) {
    int nd = blockIdx.x * blockDim.x + threadIdx.x;
    if (nd >= n) return;
    float dv = dinv[nd];
    const float4* ar = reinterpret_cast<const float4*>(agg + (size_t)nd * FHID);
    float4* pp = reinterpret_cast<float4*>(p + (size_t)nd * FHID);
    float4* ap = reinterpret_cast<float4*>(aggp + (size_t)nd * FHID);
    const float4* bv = reinterpret_cast<const float4*>(b1);
#pragma unroll
    for (int j = 0; j < FHID / 4; ++j) {
        float4 v = ar[j];
        float4 b = bv[j];
        float4 r;
        r.x = fmaxf(fmaf(v.x, dv, b.x), 0.0f) * dv;
        r.y = fmaxf(fmaf(v.y, dv, b.y), 0.0f) * dv;
        r.z = fmaxf(fmaf(v.z, dv, b.z), 0.0f) * dv;
        r.w = fmaxf(fmaf(v.w, dv, b.w), 0.0f) * dv;
        pp[j] = r;
        ap[j] = r;  // self-loop init for layer 2
    }
}

// ---------------- finish layer 2: out = log_softmax((aggp*dinv) @ W2 + b2) ----------

__global__ __launch_bounds__(256) void k_finish2(const float* __restrict__ aggp,
                                                 const float* __restrict__ dinv,
                                                 const float* __restrict__ W2,
                                                 const float* __restrict__ b2,
                                                 float* __restrict__ out, int n) {
    __shared__ float Wl[FHID * FOUT];
    __shared__ float bl[FOUT];
    for (int i = threadIdx.x; i < FHID * FOUT; i += 256) Wl[i] = W2[i];
    if (threadIdx.x < FOUT) bl[threadIdx.x] = b2[threadIdx.x];
    __syncthreads();

    int nd = blockIdx.x * 256 + threadIdx.x;
    if (nd >= n) return;

    float dv = dinv[nd];
    float q[FHID];
    const float4* ap = reinterpret_cast<const float4*>(aggp + (size_t)nd * FHID);
#pragma unroll
    for (int j = 0; j < FHID / 4; ++j) {
        float4 v = ap[j];
        q[4 * j + 0] = v.x * dv;
        q[4 * j + 1] = v.y * dv;
        q[4 * j + 2] = v.z * dv;
        q[4 * j + 3] = v.w * dv;
    }

    float acc[FOUT];
#pragma unroll
    for (int o = 0; o < FOUT; ++o) acc[o] = bl[o];
#pragma unroll
    for (int k = 0; k < FHID; ++k) {
        float qs = q[k];
        const float* wrow = &Wl[k * FOUT];
#pragma unroll
        for (int o = 0; o < FOUT; ++o) acc[o] = fmaf(qs, wrow[o], acc[o]);
    }

    float m = acc[0];
#pragma unroll
    for (int o = 1; o < FOUT; ++o) m = fmaxf(m, acc[o]);
    float ssum = 0.0f;
#pragma unroll
    for (int o = 0; o < FOUT; ++o) ssum += expf(acc[o] - m);
    float lse = m + logf(ssum);

    float4* op = reinterpret_cast<float4*>(out + (size_t)nd * FOUT);
#pragma unroll
    for (int t = 0; t < FOUT / 4; ++t) {
        float4 v;
        v.x = acc[4 * t + 0] - lse;
        v.y = acc[4 * t + 1] - lse;
        v.z = acc[4 * t + 2] - lse;
        v.w = acc[4 * t + 3] - lse;
        op[t] = v;
    }
}

// ---------------- launch ----------------

extern "C" void kernel_launch(void* const* d_in, const int* in_sizes, int n_in,
                              void* d_out, int out_size, void* d_ws, size_t ws_size,
                              hipStream_t stream) {
    const float* x  = (const float*)d_in[0];
    const int*   ei = (const int*)d_in[1];
    const float* W1 = (const float*)d_in[2];
    const float* b1 = (const float*)d_in[3];
    const float* W2 = (const float*)d_in[4];
    const float* b2 = (const float*)d_in[5];

    const int fh = in_sizes[3];              // 16
    const int fi = in_sizes[2] / fh;         // 512
    const int n  = in_sizes[0] / fi;         // 100000
    const int E  = in_sizes[1] / 2;          // 3200000
    (void)n_in; (void)out_size; (void)ws_size;

    const int* src = ei;
    const int* dst = ei + E;

    char* w = (char*)d_ws;
    int*   cnt  = (int*)w;    w += (size_t)n * 4;
    float* dinv = (float*)w;  w += (size_t)n * 4;
    float* g    = (float*)w;  w += (size_t)n * FHID * 4;
    float* agg  = (float*)w;  w += (size_t)n * FHID * 4;
    float* p    = (float*)w;  w += (size_t)n * FHID * 4;
    float* aggp = (float*)w;

    float* out = (float*)d_out;

    const int TB = 256;
    const int nb_e = (E + TB - 1) / TB;
    const int nb_n = (n + TB - 1) / TB;
    const int nb_s = (int)(((long long)E * FHID + TB - 1) / TB);

    hipMemsetAsync(cnt, 0, (size_t)n * 4, stream);
    k_count<<<nb_e, TB, 0, stream>>>(dst, cnt, E);
    k_rsqrt<<<nb_n, TB, 0, stream>>>(cnt, dinv, n);

    k_gemm1<<<nb_n, TB, 0, stream>>>(x, W1, dinv, g, agg, n);
    k_scat<false><<<nb_s, TB, 0, stream>>>(src, dst, g, agg, E);
    k_finish1<<<nb_n, TB, 0, stream>>>(agg, dinv, b1, p, aggp, n);
    k_scat<true><<<nb_s, TB, 0, stream>>>(src, dst, p, aggp, E);
    k_finish2<<<nb_n, TB, 0, stream>>>(aggp, dinv, W2, b2, out, n);
}